// Round 1
// baseline (304.266 us; speedup 1.0000x reference)
//
#include <hip/hip_runtime.h>
#include <math.h>

#define NQ 8192
#define D 768
#define P 64
#define K 4
#define PD 8
#define F4_PER_K ((PD*D)/4)    /* 1536 float4 per selected prompt block */
#define F4_PER_N ((K*PD*D)/4)  /* 6144 float4 per query row of output  */
#define SEL_ELEMS ((size_t)NQ * K * PD * D)  /* 201326592 */

// ---------------- kernel 1: normalize keys, emit kn [64][768] and knT [768][64]
__global__ __launch_bounds__(256) void normalize_keys(const float* __restrict__ keys,
                                                      float* __restrict__ kn,
                                                      float* __restrict__ knT) {
    int b = blockIdx.x;           // key row
    int t = threadIdx.x;
    __shared__ float red[256];
    float ss = 0.f;
    for (int j = t; j < D; j += 256) { float v = keys[b * D + j]; ss = fmaf(v, v, ss); }
    red[t] = ss; __syncthreads();
    for (int s = 128; s > 0; s >>= 1) { if (t < s) red[t] += red[t + s]; __syncthreads(); }
    float inv = 1.f / fmaxf(sqrtf(red[0]), 1e-12f);
    for (int j = t; j < D; j += 256) {
        float v = keys[b * D + j] * inv;
        kn[b * D + j]  = v;
        knT[j * P + b] = v;
    }
}

// ---------------- kernel 2: per-query dots vs all 64 keys, top-4 vote, qsum partials
// 256 blocks x 256 threads; wave w handles 8 queries; lane = key index.
__global__ __launch_bounds__(256) void sim_topk(const float* __restrict__ q,
                                                const float* __restrict__ knT,
                                                int* __restrict__ g_counts,
                                                float* __restrict__ partial) {
    __shared__ float qs[4][D];   // per-wave qn accumulator (12 KB)
    __shared__ int   cnt[P];
    int t = threadIdx.x;
    int w = t >> 6, lane = t & 63;

    for (int j = t; j < 4 * D; j += 256) ((float*)qs)[j] = 0.f;
    if (t < P) cnt[t] = 0;
    __syncthreads();

    int qbase = blockIdx.x * 32 + w * 8;

    float acc[8], ssq[8];
    #pragma unroll
    for (int i = 0; i < 8; ++i) { acc[i] = 0.f; ssq[i] = 0.f; }

    const float4* q4 = (const float4*)q;
    for (int d4 = 0; d4 < D / 4; ++d4) {
        int dd = d4 * 4;
        float k0 = knT[(dd + 0) * P + lane];
        float k1 = knT[(dd + 1) * P + lane];
        float k2 = knT[(dd + 2) * P + lane];
        float k3 = knT[(dd + 3) * P + lane];
        #pragma unroll
        for (int qi = 0; qi < 8; ++qi) {
            float4 v = q4[(size_t)(qbase + qi) * (D / 4) + d4];   // wave-uniform broadcast
            acc[qi] = fmaf(v.x, k0, fmaf(v.y, k1, fmaf(v.z, k2, fmaf(v.w, k3, acc[qi]))));
            ssq[qi] = fmaf(v.x, v.x, fmaf(v.y, v.y, fmaf(v.z, v.z, fmaf(v.w, v.w, ssq[qi]))));
        }
    }

    #pragma unroll
    for (int qi = 0; qi < 8; ++qi) {
        // ---- top-4 key indices over 64 lanes (ties -> lowest index)
        float mv = acc[qi];     // per-lane live value (masked to -inf once picked)
        int w0, w1, w2, w3;
        #pragma unroll
        for (int r = 0; r < 4; ++r) {
            float v = mv; int idx = lane;
            #pragma unroll
            for (int off = 32; off > 0; off >>= 1) {
                float ov = __shfl_xor(v, off);
                int   oi = __shfl_xor(idx, off);
                if (ov > v || (ov == v && oi < idx)) { v = ov; idx = oi; }
            }
            if (r == 0) w0 = idx; else if (r == 1) w1 = idx; else if (r == 2) w2 = idx; else w3 = idx;
            if (lane == idx) mv = -INFINITY;
        }
        if (lane == 0) {
            atomicAdd(&cnt[w0], 1); atomicAdd(&cnt[w1], 1);
            atomicAdd(&cnt[w2], 1); atomicAdd(&cnt[w3], 1);
        }
        // ---- qsum contribution (needs the true query norm)
        float inv = 1.f / fmaxf(sqrtf(ssq[qi]), 1e-12f);
        const float* qrow = q + (size_t)(qbase + qi) * D;
        for (int j = lane; j < D; j += 64) qs[w][j] += qrow[j] * inv;  // lane-owned, race-free
    }
    __syncthreads();

    if (t < P) atomicAdd(&g_counts[t], cnt[t]);
    for (int j = t; j < D; j += 256)
        partial[(size_t)blockIdx.x * D + j] = qs[0][j] + qs[1][j] + qs[2][j] + qs[3][j];
}

// ---------------- kernel 3: reduce qsum, global top-4 of counts, loss
__global__ __launch_bounds__(256) void finalize(const float* __restrict__ partial,
                                                const int* __restrict__ g_counts,
                                                const float* __restrict__ kn,
                                                int* __restrict__ top_idx,
                                                float* __restrict__ loss_out) {
    __shared__ float qsum[D];
    __shared__ int   sel[K];
    __shared__ int   c[P];
    __shared__ float red[256];
    int t = threadIdx.x;

    for (int j = t; j < D; j += 256) {
        float s = 0.f;
        for (int b = 0; b < 256; ++b) s += partial[(size_t)b * D + j];
        qsum[j] = s;
    }
    if (t < P) c[t] = g_counts[t];
    __syncthreads();

    if (t == 0) {
        for (int r = 0; r < K; ++r) {
            int best = 0, bv = c[0];
            for (int i = 1; i < P; ++i) if (c[i] > bv) { bv = c[i]; best = i; }  // > keeps lowest idx on tie
            sel[r] = best; top_idx[r] = best; c[best] = -1;
        }
    }
    __syncthreads();

    float part = 0.f;
    #pragma unroll
    for (int r = 0; r < K; ++r) {
        const float* kr = kn + (size_t)sel[r] * D;
        for (int j = t; j < D; j += 256) part = fmaf(kr[j], qsum[j], part);
    }
    red[t] = part; __syncthreads();
    for (int s = 128; s > 0; s >>= 1) { if (t < s) red[t] += red[t + s]; __syncthreads(); }
    if (t == 0) loss_out[0] = red[0] / (float)NQ;
}

// ---------------- kernel 4: broadcast-write selected prompts to all 8192 queries
__global__ __launch_bounds__(256) void writer(const float* __restrict__ prompts,
                                              const int* __restrict__ top_idx,
                                              float* __restrict__ out) {
    int n = blockIdx.x;
    int t = threadIdx.x;
    int i0 = top_idx[0], i1 = top_idx[1], i2 = top_idx[2], i3 = top_idx[3];
    const float4* p4 = (const float4*)prompts;
    float4* o4 = (float4*)out + (size_t)n * F4_PER_N;
    #pragma unroll
    for (int j = 0; j < 24; ++j) {
        int idx = t + j * 256;                 // 0..6143
        int k   = idx / F4_PER_K;              // 0..3
        int off = idx - k * F4_PER_K;
        int src = (k == 0) ? i0 : (k == 1) ? i1 : (k == 2) ? i2 : i3;
        o4[idx] = p4[(size_t)src * F4_PER_K + off];
    }
}

extern "C" void kernel_launch(void* const* d_in, const int* in_sizes, int n_in,
                              void* d_out, int out_size, void* d_ws, size_t ws_size,
                              hipStream_t stream) {
    const float* queries = (const float*)d_in[0];   // [8192, 768]
    const float* keys    = (const float*)d_in[1];   // [64, 768]
    const float* prompts = (const float*)d_in[2];   // [64, 8, 768]
    float* out = (float*)d_out;                     // [8192*32*768] + [1]
    float* ws  = (float*)d_ws;

    // ws layout (float units)
    float* knT     = ws;                 // 768*64  = 49152
    float* kn      = ws + 49152;         // 64*768  = 49152
    int*   counts  = (int*)(ws + 98304); // 64 ints
    int*   top_idx = (int*)(ws + 98368); // 4 ints
    float* partial = ws + 98432;         // 256*768 = 196608

    hipMemsetAsync(counts, 0, P * sizeof(int), stream);
    normalize_keys<<<P, 256, 0, stream>>>(keys, kn, knT);
    sim_topk<<<256, 256, 0, stream>>>(queries, knT, counts, partial);
    finalize<<<1, 256, 0, stream>>>(partial, counts, kn, top_idx, out + SEL_ELEMS);
    writer<<<NQ, 256, 0, stream>>>(prompts, top_idx, out);
}

// Round 3
// 213.517 us; speedup vs baseline: 1.4250x; 1.4250x over previous
//
#include <hip/hip_runtime.h>
#include <math.h>

#define NQ 8192
#define D 768
#define DF4 (D/4)              /* 192 float4 per row */
#define P 64
#define K 4
#define PD 8
#define QPB 16                 /* queries per block in sim kernel */
#define NBLK (NQ/QPB)          /* 512 sim blocks */
#define F4_PER_K ((PD*D)/4)    /* 1536 float4 per selected prompt block */
#define F4_PER_N ((K*PD*D)/4)  /* 6144 float4 per query row of output  */
#define SEL_ELEMS ((size_t)NQ * K * PD * D)  /* 201326592 */

typedef float f32x4 __attribute__((ext_vector_type(4)));

// ---------------- kernel 1: normalize keys -> knT [768][64] (column-major for coalesced lane=key reads)
__global__ __launch_bounds__(256) void normalize_keys(const float* __restrict__ keys,
                                                      float* __restrict__ knT) {
    int b = blockIdx.x;           // key row
    int t = threadIdx.x;
    __shared__ float red[256];
    float ss = 0.f;
    for (int j = t; j < D; j += 256) { float v = keys[b * D + j]; ss = fmaf(v, v, ss); }
    red[t] = ss; __syncthreads();
    for (int s = 128; s > 0; s >>= 1) { if (t < s) red[t] += red[t + s]; __syncthreads(); }
    float inv = 1.f / fmaxf(sqrtf(red[0]), 1e-12f);
    for (int j = t; j < D; j += 256) knT[j * P + b] = keys[b * D + j] * inv;
}

// ---------------- kernel 2: sims, per-query top-4 vote, per-key column sums (for loss)
// 512 blocks x 256 threads (4 waves). Block owns 16 queries (staged in LDS).
// Wave w computes partial dots over D-quarter [w*192, w*192+192), lane = key.
__global__ __launch_bounds__(256) void sim_topk(const float* __restrict__ q,
                                                const float* __restrict__ knT,
                                                int* __restrict__ g_counts,
                                                float* __restrict__ colpartial) {
    __shared__ float4 qt[QPB * DF4];      // 48 KB: 16 query rows
    __shared__ float  simw[4][QPB][P];    // 16 KB: per-wave partial dots
    __shared__ float  colw[4][P];         // per-wave column sums
    __shared__ int    cnt[P];
    int t = threadIdx.x;
    int w = t >> 6, lane = t & 63;
    int qbase = blockIdx.x * QPB;

    // stage 16 query rows, fully coalesced
    const float4* q4 = (const float4*)q + (size_t)qbase * DF4;
    #pragma unroll
    for (int i = 0; i < (QPB * DF4) / 256; ++i) qt[t + i * 256] = q4[t + i * 256];
    if (t < P) cnt[t] = 0;
    __syncthreads();

    // partial dots over this wave's D-quarter
    float acc[QPB];
    #pragma unroll
    for (int i = 0; i < QPB; ++i) acc[i] = 0.f;
    int d4base = w * 48;                  // float4 index base within a row
    for (int d4 = 0; d4 < 48; ++d4) {
        int dd = (d4base + d4) * 4;
        float k0 = knT[(dd + 0) * P + lane];
        float k1 = knT[(dd + 1) * P + lane];
        float k2 = knT[(dd + 2) * P + lane];
        float k3 = knT[(dd + 3) * P + lane];
        #pragma unroll
        for (int qi = 0; qi < QPB; ++qi) {
            float4 v = qt[qi * DF4 + d4base + d4];    // uniform -> LDS broadcast
            acc[qi] = fmaf(v.x, k0, fmaf(v.y, k1, fmaf(v.z, k2, fmaf(v.w, k3, acc[qi]))));
        }
    }
    #pragma unroll
    for (int qi = 0; qi < QPB; ++qi) simw[w][qi][lane] = acc[qi];
    __syncthreads();

    // wave w finalizes queries w*4 .. w*4+3
    float colacc = 0.f;
    #pragma unroll
    for (int s = 0; s < 4; ++s) {
        int qi = w * 4 + s;
        // full dot for (query qi, key lane)
        float dot = simw[0][qi][lane] + simw[1][qi][lane] + simw[2][qi][lane] + simw[3][qi][lane];
        // ssq via lane-split over the row (3 float4 per lane) + butterfly
        float ss = 0.f;
        #pragma unroll
        for (int j = 0; j < 3; ++j) {
            float4 v = qt[qi * DF4 + lane + j * 64];
            ss = fmaf(v.x, v.x, fmaf(v.y, v.y, fmaf(v.z, v.z, fmaf(v.w, v.w, ss))));
        }
        #pragma unroll
        for (int off = 32; off > 0; off >>= 1) ss += __shfl_xor(ss, off);
        float inv = 1.f / fmaxf(sqrtf(ss), 1e-12f);
        float sim = dot * inv;
        colacc += sim;
        // top-4 over 64 lanes, ties -> lowest key index (matches lax.top_k)
        float mv = sim;
        int w0, w1, w2, w3;
        #pragma unroll
        for (int r = 0; r < 4; ++r) {
            float v = mv; int idx = lane;
            #pragma unroll
            for (int off = 32; off > 0; off >>= 1) {
                float ov = __shfl_xor(v, off);
                int   oi = __shfl_xor(idx, off);
                if (ov > v || (ov == v && oi < idx)) { v = ov; idx = oi; }
            }
            if (r == 0) w0 = idx; else if (r == 1) w1 = idx; else if (r == 2) w2 = idx; else w3 = idx;
            if (lane == idx) mv = -INFINITY;
        }
        if (lane == 0) {
            atomicAdd(&cnt[w0], 1); atomicAdd(&cnt[w1], 1);
            atomicAdd(&cnt[w2], 1); atomicAdd(&cnt[w3], 1);
        }
    }
    colw[w][lane] = colacc;
    __syncthreads();

    if (t < P) {
        atomicAdd(&g_counts[t], cnt[t]);
        colpartial[(size_t)blockIdx.x * P + t] = colw[0][t] + colw[1][t] + colw[2][t] + colw[3][t];
    }
}

// ---------------- kernel 3: reduce column sums, top-4 of counts, loss
__global__ __launch_bounds__(256) void finalize(const float* __restrict__ colpartial,
                                                const int* __restrict__ g_counts,
                                                int* __restrict__ top_idx,
                                                float* __restrict__ loss_out) {
    __shared__ float colg[4][P];
    __shared__ float colsum[P];
    int t = threadIdx.x;
    int key = t & 63, grp = t >> 6;       // 4 groups x 128 blocks each
    float s = 0.f;
    for (int b = grp * (NBLK / 4); b < (grp + 1) * (NBLK / 4); ++b)
        s += colpartial[(size_t)b * P + key];
    colg[grp][key] = s;
    __syncthreads();
    if (t < P) colsum[t] = colg[0][t] + colg[1][t] + colg[2][t] + colg[3][t];
    __syncthreads();
    if (t == 0) {
        int c[P];
        #pragma unroll
        for (int i = 0; i < P; ++i) c[i] = g_counts[i];
        float loss = 0.f;
        for (int r = 0; r < K; ++r) {
            int best = 0, bv = c[0];
            for (int i = 1; i < P; ++i) if (c[i] > bv) { bv = c[i]; best = i; }  // > keeps lowest idx on tie
            top_idx[r] = best; loss += colsum[best]; c[best] = -1;
        }
        loss_out[0] = loss / (float)NQ;
    }
}

// ---------------- kernel 4: broadcast-write selected prompts to all 8192 queries
__global__ __launch_bounds__(256) void writer(const float* __restrict__ prompts,
                                              const int* __restrict__ top_idx,
                                              float* __restrict__ out) {
    int n = blockIdx.x;
    int t = threadIdx.x;
    const f32x4* p4 = (const f32x4*)prompts;
    f32x4* o4 = (f32x4*)out + (size_t)n * F4_PER_N;
    #pragma unroll
    for (int k = 0; k < K; ++k) {
        const f32x4* src = p4 + (size_t)top_idx[k] * F4_PER_K;
        #pragma unroll
        for (int jj = 0; jj < 6; ++jj) {
            int off = jj * 256 + t;        // 0..1535, contiguous per k
            __builtin_nontemporal_store(src[off], &o4[k * F4_PER_K + off]);
        }
    }
}

extern "C" void kernel_launch(void* const* d_in, const int* in_sizes, int n_in,
                              void* d_out, int out_size, void* d_ws, size_t ws_size,
                              hipStream_t stream) {
    const float* queries = (const float*)d_in[0];   // [8192, 768]
    const float* keys    = (const float*)d_in[1];   // [64, 768]
    const float* prompts = (const float*)d_in[2];   // [64, 8, 768]
    float* out = (float*)d_out;                     // [8192*32*768] + [1]
    float* ws  = (float*)d_ws;

    // ws layout (float units)
    float* knT        = ws;                       // 768*64 = 49152 floats
    float* colpartial = ws + 49152;               // 512*64 = 32768 floats
    int*   counts     = (int*)(ws + 49152 + 32768);  // 64 ints
    int*   top_idx    = (int*)(ws + 49152 + 32768 + 64);  // 4 ints

    (void)hipMemsetAsync(counts, 0, P * sizeof(int), stream);
    normalize_keys<<<P, 256, 0, stream>>>(keys, knT);
    sim_topk<<<NBLK, 256, 0, stream>>>(queries, knT, counts, colpartial);
    finalize<<<1, 256, 0, stream>>>(colpartial, counts, top_idx, out + SEL_ELEMS);
    writer<<<NQ, 256, 0, stream>>>(prompts, top_idx, out);
}

// Round 4
// 202.395 us; speedup vs baseline: 1.5033x; 1.0550x over previous
//
#include <hip/hip_runtime.h>
#include <math.h>

#define NQ 8192
#define D 768
#define DF4 (D/4)              /* 192 float4 per row */
#define P 64
#define K 4
#define PD 8
#define QPB 16                 /* queries per block in sim kernel */
#define NBLK (NQ/QPB)          /* 512 sim blocks */
#define ROWS_PER_WB 4          /* writer: query rows per block */
#define F4_PER_K ((PD*D)/4)    /* 1536 float4 per selected prompt block */
#define F4_PER_N ((K*PD*D)/4)  /* 6144 float4 per query row of output  */
#define SEL_ELEMS ((size_t)NQ * K * PD * D)  /* 201326592 */

typedef float f32x4 __attribute__((ext_vector_type(4)));

// ---------------- kernel 1: normalize keys -> knT [768][64]; also zero the vote counters
__global__ __launch_bounds__(256) void normalize_keys(const float* __restrict__ keys,
                                                      float* __restrict__ knT,
                                                      int* __restrict__ g_counts) {
    int b = blockIdx.x;           // key row
    int t = threadIdx.x;
    if (b == 0 && t < P) g_counts[t] = 0;   // replaces the memset dispatch
    __shared__ float red[256];
    float ss = 0.f;
    for (int j = t; j < D; j += 256) { float v = keys[b * D + j]; ss = fmaf(v, v, ss); }
    red[t] = ss; __syncthreads();
    for (int s = 128; s > 0; s >>= 1) { if (t < s) red[t] += red[t + s]; __syncthreads(); }
    float inv = 1.f / fmaxf(sqrtf(red[0]), 1e-12f);
    for (int j = t; j < D; j += 256) knT[j * P + b] = keys[b * D + j] * inv;
}

// ---------------- kernel 2: sims, per-query top-4 vote, per-key column sums (for loss)
// 512 blocks x 256 threads (4 waves). Block owns 16 queries (staged in LDS).
// Wave w computes partial dots over D-quarter [w*192, w*192+192), lane = key.
__global__ __launch_bounds__(256) void sim_topk(const float* __restrict__ q,
                                                const float* __restrict__ knT,
                                                int* __restrict__ g_counts,
                                                float* __restrict__ colpartial) {
    __shared__ float4 qt[QPB * DF4];      // 48 KB: 16 query rows
    __shared__ float  simw[4][QPB][P];    // 16 KB: per-wave partial dots
    __shared__ float  colw[4][P];         // per-wave column sums
    __shared__ int    cnt[P];
    int t = threadIdx.x;
    int w = t >> 6, lane = t & 63;
    int qbase = blockIdx.x * QPB;

    // stage 16 query rows, fully coalesced
    const float4* q4 = (const float4*)q + (size_t)qbase * DF4;
    #pragma unroll
    for (int i = 0; i < (QPB * DF4) / 256; ++i) qt[t + i * 256] = q4[t + i * 256];
    if (t < P) cnt[t] = 0;
    __syncthreads();

    // partial dots over this wave's D-quarter
    float acc[QPB];
    #pragma unroll
    for (int i = 0; i < QPB; ++i) acc[i] = 0.f;
    int d4base = w * 48;                  // float4 index base within a row
    for (int d4 = 0; d4 < 48; ++d4) {
        int dd = (d4base + d4) * 4;
        float k0 = knT[(dd + 0) * P + lane];
        float k1 = knT[(dd + 1) * P + lane];
        float k2 = knT[(dd + 2) * P + lane];
        float k3 = knT[(dd + 3) * P + lane];
        #pragma unroll
        for (int qi = 0; qi < QPB; ++qi) {
            float4 v = qt[qi * DF4 + d4base + d4];    // uniform -> LDS broadcast
            acc[qi] = fmaf(v.x, k0, fmaf(v.y, k1, fmaf(v.z, k2, fmaf(v.w, k3, acc[qi]))));
        }
    }
    #pragma unroll
    for (int qi = 0; qi < QPB; ++qi) simw[w][qi][lane] = acc[qi];
    __syncthreads();

    // wave w finalizes queries w*4 .. w*4+3
    float colacc = 0.f;
    #pragma unroll
    for (int s = 0; s < 4; ++s) {
        int qi = w * 4 + s;
        // full dot for (query qi, key lane)
        float dot = simw[0][qi][lane] + simw[1][qi][lane] + simw[2][qi][lane] + simw[3][qi][lane];
        // ssq via lane-split over the row (3 float4 per lane) + butterfly
        float ss = 0.f;
        #pragma unroll
        for (int j = 0; j < 3; ++j) {
            float4 v = qt[qi * DF4 + lane + j * 64];
            ss = fmaf(v.x, v.x, fmaf(v.y, v.y, fmaf(v.z, v.z, fmaf(v.w, v.w, ss))));
        }
        #pragma unroll
        for (int off = 32; off > 0; off >>= 1) ss += __shfl_xor(ss, off);
        float inv = 1.f / fmaxf(sqrtf(ss), 1e-12f);
        float sim = dot * inv;
        colacc += sim;
        // top-4 over 64 lanes, ties -> lowest key index (matches lax.top_k)
        float mv = sim;
        int w0, w1, w2, w3;
        #pragma unroll
        for (int r = 0; r < 4; ++r) {
            float v = mv; int idx = lane;
            #pragma unroll
            for (int off = 32; off > 0; off >>= 1) {
                float ov = __shfl_xor(v, off);
                int   oi = __shfl_xor(idx, off);
                if (ov > v || (ov == v && oi < idx)) { v = ov; idx = oi; }
            }
            if (r == 0) w0 = idx; else if (r == 1) w1 = idx; else if (r == 2) w2 = idx; else w3 = idx;
            if (lane == idx) mv = -INFINITY;
        }
        if (lane == 0) {
            atomicAdd(&cnt[w0], 1); atomicAdd(&cnt[w1], 1);
            atomicAdd(&cnt[w2], 1); atomicAdd(&cnt[w3], 1);
        }
    }
    colw[w][lane] = colacc;
    __syncthreads();

    if (t < P) {
        atomicAdd(&g_counts[t], cnt[t]);
        colpartial[(size_t)blockIdx.x * P + t] = colw[0][t] + colw[1][t] + colw[2][t] + colw[3][t];
    }
}

// ---------------- kernel 3: reduce column sums, top-4 of counts, loss
__global__ __launch_bounds__(256) void finalize(const float* __restrict__ colpartial,
                                                const int* __restrict__ g_counts,
                                                int* __restrict__ top_idx,
                                                float* __restrict__ loss_out) {
    __shared__ float colg[4][P];
    __shared__ float colsum[P];
    int t = threadIdx.x;
    int key = t & 63, grp = t >> 6;       // 4 groups x 128 blocks each
    float s = 0.f;
    for (int b = grp * (NBLK / 4); b < (grp + 1) * (NBLK / 4); ++b)
        s += colpartial[(size_t)b * P + key];
    colg[grp][key] = s;
    __syncthreads();
    if (t < P) colsum[t] = colg[0][t] + colg[1][t] + colg[2][t] + colg[3][t];
    __syncthreads();
    if (t == 0) {
        int c[P];
        #pragma unroll
        for (int i = 0; i < P; ++i) c[i] = g_counts[i];
        float loss = 0.f;
        for (int r = 0; r < K; ++r) {
            int best = 0, bv = c[0];
            for (int i = 1; i < P; ++i) if (c[i] > bv) { bv = c[i]; best = i; }  // > keeps lowest idx on tie
            top_idx[r] = best; loss += colsum[best]; c[best] = -1;
        }
        loss_out[0] = loss / (float)NQ;
    }
}

// ---------------- kernel 4: broadcast-write selected prompts, 4 query rows per block
// Plain (cached) stores — the harness fill hits 6.8 TB/s with plain stores; nt dropped.
// Each loaded float4 is stored 4x, so vmem issue slots are 1 load : 4 stores.
__global__ __launch_bounds__(256) void writer(const float* __restrict__ prompts,
                                              const int* __restrict__ top_idx,
                                              float* __restrict__ out) {
    int b = blockIdx.x;                   // 2048 blocks
    int t = threadIdx.x;
    int i0 = top_idx[0], i1 = top_idx[1], i2 = top_idx[2], i3 = top_idx[3];
    const f32x4* p4 = (const f32x4*)prompts;
    f32x4* o4 = (f32x4*)out + (size_t)b * ROWS_PER_WB * F4_PER_N;
    #pragma unroll
    for (int k = 0; k < K; ++k) {
        int src = (k == 0) ? i0 : (k == 1) ? i1 : (k == 2) ? i2 : i3;
        const f32x4* sp = p4 + (size_t)src * F4_PER_K;
        #pragma unroll
        for (int jj = 0; jj < 6; ++jj) {
            int off = jj * 256 + t;        // 0..1535, contiguous per k
            f32x4 v = sp[off];
            #pragma unroll
            for (int r = 0; r < ROWS_PER_WB; ++r)
                o4[(size_t)r * F4_PER_N + k * F4_PER_K + off] = v;
        }
    }
}

extern "C" void kernel_launch(void* const* d_in, const int* in_sizes, int n_in,
                              void* d_out, int out_size, void* d_ws, size_t ws_size,
                              hipStream_t stream) {
    const float* queries = (const float*)d_in[0];   // [8192, 768]
    const float* keys    = (const float*)d_in[1];   // [64, 768]
    const float* prompts = (const float*)d_in[2];   // [64, 8, 768]
    float* out = (float*)d_out;                     // [8192*32*768] + [1]
    float* ws  = (float*)d_ws;

    // ws layout (float units)
    float* knT        = ws;                       // 768*64 = 49152 floats
    float* colpartial = ws + 49152;               // 512*64 = 32768 floats
    int*   counts     = (int*)(ws + 49152 + 32768);       // 64 ints
    int*   top_idx    = (int*)(ws + 49152 + 32768 + 64);  // 4 ints

    normalize_keys<<<P, 256, 0, stream>>>(keys, knT, counts);
    sim_topk<<<NBLK, 256, 0, stream>>>(queries, knT, counts, colpartial);
    finalize<<<1, 256, 0, stream>>>(colpartial, counts, top_idx, out + SEL_ELEMS);
    writer<<<NQ / ROWS_PER_WB, 256, 0, stream>>>(prompts, top_idx, out);
}